// Round 10
// baseline (975.901 us; speedup 1.0000x reference)
//
#include <hip/hip_runtime.h>
#include <math.h>

#define Bq   4
#define Sq   2048
#define CIN  512
#define NH   8
#define CH   64
#define HC   512   // NH*CH

typedef __attribute__((ext_vector_type(8))) short bf16x8;
typedef __attribute__((ext_vector_type(4))) float f32x4;

__device__ __forceinline__ f32x4 MFMA(bf16x8 a, bf16x8 b, f32x4 c) {
    return __builtin_amdgcn_mfma_f32_16x16x32_bf16(a, b, c, 0, 0, 0);
}

// Exact split: f = hi + lo + O(2^-15 |f|).
__device__ __forceinline__ void splitf(float f, unsigned short& h, unsigned short& l) {
    unsigned int u = __float_as_uint(f);
    h = (unsigned short)(u >> 16);
    float fh = __uint_as_float(u & 0xFFFF0000u);
    l = (unsigned short)(__float_as_uint(f - fh) >> 16);
}

__device__ __forceinline__ void cvt4(float4 v, ushort4& h, ushort4& l) {
    splitf(v.x, h.x, l.x); splitf(v.y, h.y, l.y);
    splitf(v.z, h.z, l.z); splitf(v.w, h.w, l.w);
}

// P-store bank swizzle: XOR the 8-col group index with (row>>2)&7.
// Group-aligned -> bf16x8 reads stay contiguous and 16B-aligned.
__device__ __forceinline__ int pswz(int row, int col) {
    return col ^ (((row >> 2) & 7) << 3);
}

union FRAG8 { ushort4 u4[2]; bf16x8 v; };

// ---------------------------------------------------------------------------
// Pre-split the 5 weight matrices (each 512x512 f32) into bf16 hi/lo pairs.
// dst layout: [Wq_h|Wq_l|Wk_h|Wk_l|Wv_h|Wv_l|Wo_h|Wo_l|Wg_h|Wg_l], each 262144.
// ---------------------------------------------------------------------------
__global__ __launch_bounds__(256) void prep_split(
    const float* __restrict__ Wq, const float* __restrict__ Wk,
    const float* __restrict__ Wv, const float* __restrict__ Wo,
    const float* __restrict__ Wg, unsigned short* __restrict__ dst)
{
    const int y = blockIdx.y;
    const float* __restrict__ src =
        (y == 0) ? Wq : (y == 1) ? Wk : (y == 2) ? Wv : (y == 3) ? Wo : Wg;
    unsigned short* __restrict__ h = dst + (size_t)y * 2 * (HC * CIN);
    unsigned short* __restrict__ l = h + HC * CIN;
    const int i = (blockIdx.x * 256 + threadIdx.x) * 4;   // 256 blocks -> 262144
    float4 v = *(const float4*)&src[i];
    ushort4 hh, ll; cvt4(v, hh, ll);
    *(ushort4*)&h[i] = hh; *(ushort4*)&l[i] = ll;
}

// ---------------------------------------------------------------------------
// Fused QKV projection, bf16x3. Tile 128(M)x64(N), BK=64, 4 waves (2x2).
// Grid (64, 24): y>>3 selects Q/K/V, (y&7)*64 is the W column tile.
// W comes PRE-SPLIT (copy staging, no VALU split). A (=x) is split on stage.
// Outputs: Q fp32 (scaled 1/8); K as bf16 hi/lo (B,H,S,C); V^T hi/lo (B,H,C,S).
// ---------------------------------------------------------------------------
__global__ __launch_bounds__(256) void qkv_fused(
    const float* __restrict__ x, const unsigned short* __restrict__ Wsp,
    float* __restrict__ Qo,
    unsigned short* __restrict__ Khi, unsigned short* __restrict__ Klo,
    unsigned short* __restrict__ VThi, unsigned short* __restrict__ VTlo)
{
    __shared__ unsigned short Ah[128][72], Al[128][72];
    __shared__ unsigned short Bh[64][72],  Bl[64][72];

    const int t    = threadIdx.x;
    const int lane = t & 63;
    const int w    = t >> 6;
    const int l16  = lane & 15;
    const int g    = lane >> 4;
    const int m0   = blockIdx.x * 128;
    const int by   = blockIdx.y;
    const int sel  = by >> 3;            // 0=Q 1=K 2=V
    const int n0   = (by & 7) * 64;
    const unsigned short* __restrict__ Wh = Wsp + (size_t)sel * 2 * (HC * CIN);
    const unsigned short* __restrict__ Wl = Wh + HC * CIN;
    const int wm   = (w >> 1) * 64;
    const int wn   = (w & 1) * 32;
    const int srow = t >> 4;
    const int scol = (t & 15) * 4;

    const f32x4 z4 = {0.f, 0.f, 0.f, 0.f};
    f32x4 acc[4][2];
#pragma unroll
    for (int m = 0; m < 4; ++m)
#pragma unroll
        for (int n = 0; n < 2; ++n) acc[m][n] = z4;

    for (int kt = 0; kt < CIN; kt += 64) {
        __syncthreads();
#pragma unroll
        for (int s = 0; s < 8; ++s) {
            const int r = srow + s * 16;
            float4 av = *(const float4*)&x[(size_t)(m0 + r) * CIN + kt + scol];
            ushort4 h, l; cvt4(av, h, l);
            *(ushort4*)&Ah[r][scol] = h; *(ushort4*)&Al[r][scol] = l;
        }
#pragma unroll
        for (int s = 0; s < 4; ++s) {
            const int r = srow + s * 16;
            *(ushort4*)&Bh[r][scol] = *(const ushort4*)&Wh[(size_t)(n0 + r) * CIN + kt + scol];
            *(ushort4*)&Bl[r][scol] = *(const ushort4*)&Wl[(size_t)(n0 + r) * CIN + kt + scol];
        }
        __syncthreads();
#pragma unroll
        for (int kk = 0; kk < 2; ++kk) {
            const int ko = kk * 32 + g * 8;
            bf16x8 bh[2], bl[2];
#pragma unroll
            for (int n = 0; n < 2; ++n) {
                bh[n] = *(const bf16x8*)&Bh[wn + n * 16 + l16][ko];
                bl[n] = *(const bf16x8*)&Bl[wn + n * 16 + l16][ko];
            }
#pragma unroll
            for (int m = 0; m < 4; ++m) {
                bf16x8 ah = *(const bf16x8*)&Ah[wm + m * 16 + l16][ko];
                bf16x8 al = *(const bf16x8*)&Al[wm + m * 16 + l16][ko];
#pragma unroll
                for (int n = 0; n < 2; ++n) {
                    acc[m][n] = MFMA(ah, bh[n], acc[m][n]);
                    acc[m][n] = MFMA(ah, bl[n], acc[m][n]);
                    acc[m][n] = MFMA(al, bh[n], acc[m][n]);
                }
            }
        }
    }

#pragma unroll
    for (int m = 0; m < 4; ++m)
#pragma unroll
        for (int n = 0; n < 2; ++n) {
            const int col = n0 + wn + n * 16 + l16;   // 0..511
            const int hh  = col >> 6, d = col & 63;
#pragma unroll
            for (int r = 0; r < 4; ++r) {
                const int row = m0 + wm + m * 16 + g * 4 + r;
                const int b = row >> 11, s = row & 2047;
                float v = acc[m][n][r];
                if (sel == 0) {
                    Qo[(((size_t)b * NH + hh) * Sq + s) * CH + d] = v * 0.125f;
                } else if (sel == 1) {
                    unsigned short vh, vl; splitf(v, vh, vl);
                    const size_t idx = (((size_t)b * NH + hh) * Sq + s) * CH + d;
                    Khi[idx] = vh; Klo[idx] = vl;
                } else {
                    unsigned short vh, vl; splitf(v, vh, vl);
                    const size_t idx = (((size_t)b * NH + hh) * CH + d) * Sq + s;
                    VThi[idx] = vh; VTlo[idx] = vl;
                }
            }
        }
}

// ---------------------------------------------------------------------------
// Out-proj / gate GEMM, bf16x3, tile 128x64, grid (64,8).
// MODE 2: A = attn fp32 (split on stage); writes O as bf16 hi/lo.
// MODE 3: A = O hi/lo (copy stage);  C = sigmoid(acc+bias) * (Ohi+Olo).
// W pre-split (copy stage).
// ---------------------------------------------------------------------------
template<int MODE>
__global__ __launch_bounds__(256) void gemm_og(
    const float* __restrict__ Af,
    const unsigned short* __restrict__ Ah_g, const unsigned short* __restrict__ Al_g,
    const unsigned short* __restrict__ Wh_g, const unsigned short* __restrict__ Wl_g,
    const float* __restrict__ bias,
    unsigned short* __restrict__ OutH, unsigned short* __restrict__ OutL,
    float* __restrict__ Cout)
{
    __shared__ unsigned short Ah[128][72], Al[128][72];
    __shared__ unsigned short Bh[64][72],  Bl[64][72];

    const int t    = threadIdx.x;
    const int lane = t & 63;
    const int w    = t >> 6;
    const int l16  = lane & 15;
    const int g    = lane >> 4;
    const int m0   = blockIdx.x * 128;
    const int n0   = blockIdx.y * 64;
    const int wm   = (w >> 1) * 64;
    const int wn   = (w & 1) * 32;
    const int srow = t >> 4;
    const int scol = (t & 15) * 4;

    const f32x4 z4 = {0.f, 0.f, 0.f, 0.f};
    f32x4 acc[4][2];
#pragma unroll
    for (int m = 0; m < 4; ++m)
#pragma unroll
        for (int n = 0; n < 2; ++n) acc[m][n] = z4;

    for (int kt = 0; kt < HC; kt += 64) {
        __syncthreads();
#pragma unroll
        for (int s = 0; s < 8; ++s) {
            const int r = srow + s * 16;
            if (MODE == 2) {
                float4 av = *(const float4*)&Af[(size_t)(m0 + r) * HC + kt + scol];
                ushort4 h, l; cvt4(av, h, l);
                *(ushort4*)&Ah[r][scol] = h; *(ushort4*)&Al[r][scol] = l;
            } else {
                *(ushort4*)&Ah[r][scol] = *(const ushort4*)&Ah_g[(size_t)(m0 + r) * HC + kt + scol];
                *(ushort4*)&Al[r][scol] = *(const ushort4*)&Al_g[(size_t)(m0 + r) * HC + kt + scol];
            }
        }
#pragma unroll
        for (int s = 0; s < 4; ++s) {
            const int r = srow + s * 16;
            *(ushort4*)&Bh[r][scol] = *(const ushort4*)&Wh_g[(size_t)(n0 + r) * HC + kt + scol];
            *(ushort4*)&Bl[r][scol] = *(const ushort4*)&Wl_g[(size_t)(n0 + r) * HC + kt + scol];
        }
        __syncthreads();
#pragma unroll
        for (int kk = 0; kk < 2; ++kk) {
            const int ko = kk * 32 + g * 8;
            bf16x8 bh[2], bl[2];
#pragma unroll
            for (int n = 0; n < 2; ++n) {
                bh[n] = *(const bf16x8*)&Bh[wn + n * 16 + l16][ko];
                bl[n] = *(const bf16x8*)&Bl[wn + n * 16 + l16][ko];
            }
#pragma unroll
            for (int m = 0; m < 4; ++m) {
                bf16x8 ah = *(const bf16x8*)&Ah[wm + m * 16 + l16][ko];
                bf16x8 al = *(const bf16x8*)&Al[wm + m * 16 + l16][ko];
#pragma unroll
                for (int n = 0; n < 2; ++n) {
                    acc[m][n] = MFMA(ah, bh[n], acc[m][n]);
                    acc[m][n] = MFMA(ah, bl[n], acc[m][n]);
                    acc[m][n] = MFMA(al, bh[n], acc[m][n]);
                }
            }
        }
    }

#pragma unroll
    for (int m = 0; m < 4; ++m)
#pragma unroll
        for (int n = 0; n < 2; ++n) {
            const int col = n0 + wn + n * 16 + l16;
#pragma unroll
            for (int r = 0; r < 4; ++r) {
                const int row = m0 + wm + m * 16 + g * 4 + r;
                const float v = acc[m][n][r] + bias[col];
                if (MODE == 2) {
                    unsigned short vh, vl; splitf(v, vh, vl);
                    OutH[(size_t)row * HC + col] = vh;
                    OutL[(size_t)row * HC + col] = vl;
                } else {
                    float oh = __uint_as_float((unsigned)Ah_g[(size_t)row * HC + col] << 16);
                    float ol = __uint_as_float((unsigned)Al_g[(size_t)row * HC + col] << 16);
                    const float o = oh + ol;
                    const float gt = 1.f / (1.f + __expf(-v));
                    Cout[(size_t)row * HC + col] = gt * o;
                }
            }
        }
}

// ---------------------------------------------------------------------------
// Flash attention, bf16x3 MFMA. Grid (S/128, NH, B), 256 thr = 4 waves.
// vs round-6 (numerics bit-identical):
//  - K/V arrive PRE-SPLIT (bf16 hi/lo) -> staging is pure 8B copies; removes
//    ~128 VALU splitf-ops per lane per tile (the R8 critical path).
//  - P stores bank-swizzled (pswz): 4-way -> 2-way; expect
//    SQ_LDS_BANK_CONFLICT 1.05e7 -> <1e6.
// LDS = 36864 (K/V) + 36864 (Pbuf) + 256 = 74 KB -> 2 blocks/CU.
// ---------------------------------------------------------------------------
__global__ __launch_bounds__(256) void attn_mfma(
    const float* __restrict__ Q,
    const unsigned short* __restrict__ KhiG, const unsigned short* __restrict__ KloG,
    const unsigned short* __restrict__ VhiG, const unsigned short* __restrict__ VloG,
    const float* __restrict__ bias, const int* __restrict__ mask,
    float* __restrict__ Aout)
{
    __shared__ unsigned short Kh[64][72], Kl[64][72];
    __shared__ unsigned short Vh[64][72], Vl[64][72];
    __shared__ __align__(16) unsigned char Pbuf[4][9216];  // per-wave chunk
    __shared__ float moff[64];

    const int t    = threadIdx.x;
    const int lane = t & 63;
    const int w    = t >> 6;
    const int l16  = lane & 15;
    const int g    = lane >> 4;
    const int q0   = blockIdx.x * 128;
    const int h    = blockIdx.y;
    const int b    = blockIdx.z;
    const int wq   = w * 32;

    // per-wave chunk: Ph[32][72] | Pl[32][72] ushort, aliased by Bs[32][68] f32.
    unsigned short* Phw = (unsigned short*)(Pbuf[w]);
    unsigned short* Plw = Phw + 32 * 72;
    float*          Bsw = (float*)(Pbuf[w]);

    const float*          Qbase = Q    + (((size_t)b * NH + h) * Sq + q0 + wq) * CH;
    const unsigned short* KhB   = KhiG + ((size_t)b * NH + h) * Sq * CH;
    const unsigned short* KlB   = KloG + ((size_t)b * NH + h) * Sq * CH;
    const unsigned short* VhB   = VhiG + ((size_t)b * NH + h) * CH * Sq;
    const unsigned short* VlB   = VloG + ((size_t)b * NH + h) * CH * Sq;
    const float*          bbase = bias + (size_t)h * Sq * Sq;

    // Q fragments in registers (split once per block)
    bf16x8 qh[2][2], ql[2][2];
#pragma unroll
    for (int m = 0; m < 2; ++m)
#pragma unroll
        for (int kk = 0; kk < 2; ++kk) {
            const int row = m * 16 + l16;
            const int ko  = kk * 32 + g * 8;
            const float* p = Qbase + (size_t)row * CH + ko;
            float4 v0 = *(const float4*)p;
            float4 v1 = *(const float4*)(p + 4);
            FRAG8 fh, fl;
            cvt4(v0, fh.u4[0], fl.u4[0]);
            cvt4(v1, fh.u4[1], fl.u4[1]);
            qh[m][kk] = fh.v; ql[m][kk] = fl.v;
        }

    const f32x4 z4 = {0.f, 0.f, 0.f, 0.f};
    float m_run[2][4], l_run[2][4];
    f32x4 oacc[2][4];
#pragma unroll
    for (int m = 0; m < 2; ++m) {
#pragma unroll
        for (int r = 0; r < 4; ++r) { m_run[m][r] = -1e30f; l_run[m][r] = 0.f; }
#pragma unroll
        for (int n = 0; n < 4; ++n) oacc[m][n] = z4;
    }

    const int brow = lane >> 4;          // bias stage: 0..3
    const int bcol = (lane & 15) * 4;    // 0..60

    for (int kt = 0; kt < Sq; kt += 64) {
        __syncthreads();   // prev tile's K/V reads AND PV P-reads complete

        // stage this tile's bias rows (wave-private; overlaps staging + QK)
#pragma unroll
        for (int s = 0; s < 8; ++s) {
            const int rl = brow + s * 4;   // 0..31
            *(float4*)&Bsw[rl * 68 + bcol] =
                *(const float4*)&bbase[(size_t)(q0 + wq + rl) * Sq + kt + bcol];
        }

        // K/V tile staging: pure bf16 copies, no split work
#pragma unroll
        for (int s = 0; s < 4; ++s) {
            const int rr = (t >> 4) + s * 16;      // key-row for K, d-row for VT
            const int cc = (t & 15) * 4;
            *(ushort4*)&Kh[rr][cc] = *(const ushort4*)&KhB[(size_t)(kt + rr) * CH + cc];
            *(ushort4*)&Kl[rr][cc] = *(const ushort4*)&KlB[(size_t)(kt + rr) * CH + cc];
            *(ushort4*)&Vh[rr][cc] = *(const ushort4*)&VhB[(size_t)rr * Sq + kt + cc];
            *(ushort4*)&Vl[rr][cc] = *(const ushort4*)&VlB[(size_t)rr * Sq + kt + cc];
        }
        if (t < 64) moff[t] = (mask[b * Sq + kt + t] == 0) ? -1e8f : 0.f;
        __syncthreads();

        // ---- S = Q K^T ----
        f32x4 sfr[2][4];
#pragma unroll
        for (int m = 0; m < 2; ++m)
#pragma unroll
            for (int n = 0; n < 4; ++n) sfr[m][n] = z4;
#pragma unroll
        for (int kk = 0; kk < 2; ++kk) {
            const int ko = kk * 32 + g * 8;
            bf16x8 kh[4], kl[4];
#pragma unroll
            for (int n = 0; n < 4; ++n) {
                kh[n] = *(const bf16x8*)&Kh[n * 16 + l16][ko];
                kl[n] = *(const bf16x8*)&Kl[n * 16 + l16][ko];
            }
#pragma unroll
            for (int m = 0; m < 2; ++m)
#pragma unroll
                for (int n = 0; n < 4; ++n) {
                    sfr[m][n] = MFMA(qh[m][kk], kh[n], sfr[m][n]);
                    sfr[m][n] = MFMA(qh[m][kk], kl[n], sfr[m][n]);
                    sfr[m][n] = MFMA(ql[m][kk], kh[n], sfr[m][n]);
                }
        }

        // ---- bias (from LDS) + mask ----
#pragma unroll
        for (int m = 0; m < 2; ++m)
#pragma unroll
            for (int n = 0; n < 4; ++n) {
                const int colk = n * 16 + l16;
                const float mo = moff[colk];
#pragma unroll
                for (int r = 0; r < 4; ++r)
                    sfr[m][n][r] += Bsw[(m * 16 + g * 4 + r) * 68 + colk] + mo;
            }

        // compiler fence: bias reads (float) vs P writes (ushort) alias.
        asm volatile("" ::: "memory");

        // ---- online softmax ----
#pragma unroll
        for (int m = 0; m < 2; ++m) {
#pragma unroll
            for (int r = 0; r < 4; ++r) {
                float mx = fmaxf(fmaxf(sfr[m][0][r], sfr[m][1][r]),
                                 fmaxf(sfr[m][2][r], sfr[m][3][r]));
                mx = fmaxf(mx, __shfl_xor(mx, 1));
                mx = fmaxf(mx, __shfl_xor(mx, 2));
                mx = fmaxf(mx, __shfl_xor(mx, 4));
                mx = fmaxf(mx, __shfl_xor(mx, 8));
                const float newm = fmaxf(m_run[m][r], mx);
                const float corr = __expf(m_run[m][r] - newm);
                m_run[m][r] = newm;
                float rs = 0.f;
#pragma unroll
                for (int n = 0; n < 4; ++n) {
                    float p = __expf(sfr[m][n][r] - newm);
                    sfr[m][n][r] = p;
                    rs += p;
                }
                rs += __shfl_xor(rs, 1);
                rs += __shfl_xor(rs, 2);
                rs += __shfl_xor(rs, 4);
                rs += __shfl_xor(rs, 8);
                l_run[m][r] = l_run[m][r] * corr + rs;
#pragma unroll
                for (int n = 0; n < 4; ++n) oacc[m][n][r] *= corr;
                const int prl = m * 16 + g * 4 + r;   // wave-local P row
#pragma unroll
                for (int n = 0; n < 4; ++n) {
                    unsigned short hh, ll;
                    splitf(sfr[m][n][r], hh, ll);
                    const int pc = pswz(prl, n * 16 + l16);
                    Phw[prl * 72 + pc] = hh;
                    Plw[prl * 72 + pc] = ll;
                }
            }
        }

        // ---- O += P V  (wave-private P; in-wave DS ordering) ----
#pragma unroll
        for (int kk = 0; kk < 2; ++kk) {
            const int ko = kk * 32 + g * 8;
            bf16x8 vh[4], vl[4];
#pragma unroll
            for (int n = 0; n < 4; ++n) {
                vh[n] = *(const bf16x8*)&Vh[n * 16 + l16][ko];
                vl[n] = *(const bf16x8*)&Vl[n * 16 + l16][ko];
            }
#pragma unroll
            for (int m = 0; m < 2; ++m) {
                const int prow = m * 16 + l16;
                const int pko  = ko ^ (((prow >> 2) & 7) << 3);
                bf16x8 ph = *(const bf16x8*)&Phw[prow * 72 + pko];
                bf16x8 pl = *(const bf16x8*)&Plw[prow * 72 + pko];
#pragma unroll
                for (int n = 0; n < 4; ++n) {
                    oacc[m][n] = MFMA(ph, vh[n], oacc[m][n]);
                    oacc[m][n] = MFMA(ph, vl[n], oacc[m][n]);
                    oacc[m][n] = MFMA(pl, vh[n], oacc[m][n]);
                }
            }
        }
    }

    // ---- epilogue ----
#pragma unroll
    for (int m = 0; m < 2; ++m)
#pragma unroll
        for (int r = 0; r < 4; ++r) {
            const float inv = 1.f / l_run[m][r];
            const int row = q0 + wq + m * 16 + g * 4 + r;
#pragma unroll
            for (int n = 0; n < 4; ++n)
                Aout[((size_t)b * Sq + row) * HC + h * CH + n * 16 + l16] =
                    oacc[m][n][r] * inv;
        }
}

// ---------------------------------------------------------------------------
extern "C" void kernel_launch(void* const* d_in, const int* in_sizes, int n_in,
                              void* d_out, int out_size, void* d_ws, size_t ws_size,
                              hipStream_t stream)
{
    const float* x    = (const float*)d_in[0];
    const float* bias = (const float*)d_in[1];
    const int*   mask = (const int*)d_in[2];
    const float* Wq   = (const float*)d_in[3];
    const float* Wk   = (const float*)d_in[4];
    const float* Wv   = (const float*)d_in[5];
    const float* Wo   = (const float*)d_in[6];
    const float* bo   = (const float*)d_in[7];
    const float* Wg   = (const float*)d_in[8];
    const float* bg   = (const float*)d_in[9];
    float* out = (float*)d_out;
    float* ws  = (float*)d_ws;

    const size_t QS = (size_t)Bq * NH * Sq * CH;   // 4,194,304 elements

    // ws layout (69 MB total; R5 successfully used 80 MB):
    //   [0,QS)      : Q fp32; reused after attn as Ohi|Olo (2*QS ushorts)
    //   [QS,2QS)    : Khi | Klo (ushort)
    //   [2QS,3QS)   : VThi | VTlo (ushort)
    //   [3QS,4QS)   : attn fp32
    //   [4QS, ...)  : W splits (5 x [hi|lo] x 262144 ushorts = 5 MB)
    float*          Q    = ws;
    unsigned short* Khi  = (unsigned short*)(ws + QS);
    unsigned short* Klo  = Khi + QS;
    unsigned short* VThi = (unsigned short*)(ws + 2 * QS);
    unsigned short* VTlo = VThi + QS;
    float*          attn = ws + 3 * QS;
    unsigned short* Wsp  = (unsigned short*)(ws + 4 * QS);
    unsigned short* Ohi  = (unsigned short*)Q;     // overlay: Q dead after attn
    unsigned short* Olo  = Ohi + QS;

    const unsigned short* Woh = Wsp + (size_t)3 * 2 * (HC * CIN);
    const unsigned short* Wol = Woh + HC * CIN;
    const unsigned short* Wgh = Wsp + (size_t)4 * 2 * (HC * CIN);
    const unsigned short* Wgl = Wgh + HC * CIN;

    prep_split<<<dim3(256, 5), 256, 0, stream>>>(Wq, Wk, Wv, Wo, Wg, Wsp);

    qkv_fused<<<dim3(64, 24), 256, 0, stream>>>(x, Wsp, Q, Khi, Klo, VThi, VTlo);

    attn_mfma<<<dim3(Sq / 128, NH, Bq), 256, 0, stream>>>(
        Q, Khi, Klo, VThi, VTlo, bias, mask, attn);

    gemm_og<2><<<dim3(64, 8), 256, 0, stream>>>(
        attn, nullptr, nullptr, Woh, Wol, bo, Ohi, Olo, nullptr);
    gemm_og<3><<<dim3(64, 8), 256, 0, stream>>>(
        nullptr, Ohi, Olo, Wgh, Wgl, bg, nullptr, nullptr, out);
}